// Round 1
// baseline (2982.856 us; speedup 1.0000x reference)
//
#include <hip/hip_runtime.h>

// ---------------------------------------------------------------------------
// SmalldeckClassification: fused poker-feature net on MI355X, fp32 throughout.
// Stage C (logits GEMM + argmax) dominates: 30720x7463x512 = 234 GF fp32,
// fused argmax epilogue (no logits materialization).
// ---------------------------------------------------------------------------

#define NROWS 30720ull     // 512*60
#define NCLS  7463
#define NPAD  7552         // 59*128
#define RAWK  15360

// ws layout (all offsets 256B-aligned)
#define OFF_RAW   0ull                       // 512*15360*4  = 31,457,280
#define OFF_HF    31457280ull                // 30720*512*4  = 62,914,560
#define OFF_BPAD  94371840ull                // 512*7552*4   = 15,466,496
#define OFF_RR1   109838336ull               // 512*512*4    = 1,048,576
#define OFF_KEYS  110886912ull               // 30720*8      = 245,760

__device__ __constant__ signed char HC2[6][2] = {{0,1},{0,2},{0,3},{1,2},{1,3},{2,3}};
__device__ __constant__ signed char BC3[10][3] = {{4,5,6},{4,5,7},{4,5,8},{4,6,7},{4,6,8},
                                                  {4,7,8},{5,6,7},{5,6,8},{5,7,8},{6,7,8}};

__device__ __forceinline__ unsigned long long packKey(float v, int idx) {
    unsigned int b = __float_as_uint(v);
    b = (b & 0x80000000u) ? ~b : (b | 0x80000000u);   // order-preserving float->uint
    // low word: ~idx so that on equal value, SMALLER index wins atomicMax (numpy tie rule)
    return (((unsigned long long)b) << 32) | (unsigned long long)(0xFFFFFFFFu - (unsigned int)idx);
}

// ---------------------------------------------------------------------------
// K0: pad w_cat (512x7463) -> (512x7552) zero-padded, for aligned float4 loads
// ---------------------------------------------------------------------------
__global__ __launch_bounds__(256) void k0_bpad(const float* __restrict__ w_cat,
                                               float* __restrict__ bpad)
{
    const int c = blockIdx.x * 256 + threadIdx.x;
    const int r = blockIdx.y;
    if (c < NPAD)
        bpad[(size_t)r * NPAD + c] = (c < NCLS) ? w_cat[(size_t)r * NCLS + c] : 0.f;
}

// ---------------------------------------------------------------------------
// K1: per-m (512 blocks): card sort, combo features (rank conv + suit einsum),
//     BN(+relu) over (n=60, spatial), h1 (16->32), h2 (32->32).
//     Writes raw (512,60,256) and hflat (30720,512).
// ---------------------------------------------------------------------------
__global__ __launch_bounds__(256) void k1_features(
    const int* __restrict__ x,
    const float* __restrict__ w_suit, const float* __restrict__ b_suit,
    const float* __restrict__ g_suit, const float* __restrict__ be_suit,
    const float* __restrict__ w_rank, const float* __restrict__ b_rank,
    const float* __restrict__ g_rank, const float* __restrict__ be_rank,
    const float* __restrict__ w_h1, const float* __restrict__ b_h1,
    const float* __restrict__ w_h2, const float* __restrict__ b_h2,
    float* __restrict__ raw, float* __restrict__ hflat)
{
    __shared__ float s_wrank[400], s_wsuit[80];
    __shared__ float s_brank[16], s_bsuit[16];
    __shared__ float s_wh1[512], s_bh1[32], s_wh2[1024], s_bh2[32];
    __shared__ int   s_sr[9], s_ss[9];
    __shared__ float s_pr_sum[256], s_pr_sq[256], s_ps_sum[256], s_ps_sq[256];
    __shared__ float s_scale_r[16], s_shift_r[16], s_scale_s[16], s_shift_s[16];

    const int t = threadIdx.x;
    const int m = blockIdx.x;
    const int o = t & 15;       // conv output-channel: fixed per thread (p%16 == t%16)

    for (int i = t; i < 400;  i += 256) s_wrank[i] = w_rank[i];
    for (int i = t; i < 80;   i += 256) s_wsuit[i] = w_suit[i];
    for (int i = t; i < 512;  i += 256) s_wh1[i]   = w_h1[i];
    for (int i = t; i < 1024; i += 256) s_wh2[i]   = w_h2[i];
    if (t < 16) { s_brank[t] = b_rank[t]; s_bsuit[t] = b_suit[t]; }
    if (t < 32) { s_bh1[t] = b_h1[t]; s_bh2[t] = b_h2[t]; }

    if (t == 0) {
        int r[9], s[9];
        for (int c = 0; c < 9; ++c) { r[c] = x[m*18 + 2*c]; s[c] = x[m*18 + 2*c + 1]; }
        // stable sort by (rank, suit): hand [0..3], board [4..8]
        for (int i = 1; i < 4; ++i) {
            int kr = r[i], ks = s[i], key = kr*16 + ks, j = i - 1;
            while (j >= 0 && (r[j]*16 + s[j]) > key) { r[j+1]=r[j]; s[j+1]=s[j]; --j; }
            r[j+1]=kr; s[j+1]=ks;
        }
        for (int i = 5; i < 9; ++i) {
            int kr = r[i], ks = s[i], key = kr*16 + ks, j = i - 1;
            while (j >= 4 && (r[j]*16 + s[j]) > key) { r[j+1]=r[j]; s[j+1]=s[j]; --j; }
            r[j+1]=kr; s[j+1]=ks;
        }
        for (int c = 0; c < 9; ++c) { s_sr[c] = r[c]; s_ss[c] = s[c]; }
    }
    __syncthreads();

    // Phase 1: raw features for up to 4 (n,o) pairs per thread; BN partial sums.
    float rv[4][11], sv[4][5];
    float pr_sum = 0.f, pr_sq = 0.f, ps_sum = 0.f, ps_sq = 0.f;
#pragma unroll
    for (int u = 0; u < 4; ++u) {
        const int p = t + u*256;
        if (p < 960) {
            const int n = p >> 4;
            const int hi = n / 10, bi = n % 10;
            int cr[5], cs[5];
            cr[0] = s_sr[HC2[hi][0]]; cs[0] = s_ss[HC2[hi][0]];
            cr[1] = s_sr[HC2[hi][1]]; cs[1] = s_ss[HC2[hi][1]];
            cr[2] = s_sr[BC3[bi][0]]; cs[2] = s_ss[BC3[bi][0]];
            cr[3] = s_sr[BC3[bi][1]]; cs[3] = s_ss[BC3[bi][1]];
            cr[4] = s_sr[BC3[bi][2]]; cs[4] = s_ss[BC3[bi][2]];
            const float br = s_brank[o];
#pragma unroll
            for (int j = 0; j < 11; ++j) {           // conv VALID output position
                float v = br;
#pragma unroll
                for (int c = 0; c < 5; ++c) {
                    const int k = cr[c] - j;          // kernel tap hit by one-hot
                    if (k >= 0 && k < 5) v += s_wrank[(o*5 + c)*5 + k];
                }
                rv[u][j] = v; pr_sum += v; pr_sq += v*v;
            }
            const float bs = s_bsuit[o];
#pragma unroll
            for (int l = 0; l < 5; ++l) {
                float v = bs;
#pragma unroll
                for (int c = 0; c < 5; ++c) if (cs[c] == l) v += s_wsuit[o*5 + c];
                sv[u][l] = v; ps_sum += v; ps_sq += v*v;
            }
        } else {
#pragma unroll
            for (int j = 0; j < 11; ++j) rv[u][j] = 0.f;
#pragma unroll
            for (int l = 0; l < 5; ++l)  sv[u][l] = 0.f;
        }
    }
    s_pr_sum[t] = pr_sum; s_pr_sq[t] = pr_sq; s_ps_sum[t] = ps_sum; s_ps_sq[t] = ps_sq;
    __syncthreads();

    // Phase 2: deterministic BN stats per o (16 partial slots each)
    if (t < 16) {
        float sr = 0.f, sqr = 0.f, ss2 = 0.f, sqs = 0.f;
        for (int slot = 0; slot < 16; ++slot) {
            sr  += s_pr_sum[slot*16 + t];
            sqr += s_pr_sq [slot*16 + t];
            ss2 += s_ps_sum[slot*16 + t];
            sqs += s_ps_sq [slot*16 + t];
        }
        const float nr = 1.f / 660.f, ns = 1.f / 300.f;   // 60*11, 60*5
        const float mr = sr * nr,  varr = sqr * nr - mr*mr;
        const float ms = ss2 * ns, vars = sqs * ns - ms*ms;
        const float scr = g_rank[t] * rsqrtf(varr + 1e-5f);
        const float scs = g_suit[t] * rsqrtf(vars + 1e-5f);
        s_scale_r[t] = scr; s_shift_r[t] = be_rank[t] - mr * scr;
        s_scale_s[t] = scs; s_shift_s[t] = be_suit[t] - ms * scs;
    }
    __syncthreads();

    // Phase 3: normalize+relu, h1, h2, write raw & hflat
    const float sc_r = s_scale_r[o], sh_r = s_shift_r[o];
    const float sc_s = s_scale_s[o], sh_s = s_shift_s[o];
#pragma unroll
    for (int u = 0; u < 4; ++u) {
        const int p = t + u*256;
        if (p < 960) {
            const int n = p >> 4;
            float v[16];
#pragma unroll
            for (int j = 0; j < 11; ++j) v[j]    = fmaxf(rv[u][j]*sc_r + sh_r, 0.f);
#pragma unroll
            for (int l = 0; l < 5; ++l)  v[11+l] = fmaxf(sv[u][l]*sc_s + sh_s, 0.f);
            float* rawp = raw + ((size_t)m*15360 + n*256 + o*16);
#pragma unroll
            for (int j = 0; j < 16; ++j) rawp[j] = v[j];
            float hh[32];
#pragma unroll
            for (int jj = 0; jj < 32; ++jj) {
                float a = s_bh1[jj];
#pragma unroll
                for (int i = 0; i < 16; ++i) a = fmaf(v[i], s_wh1[i*32 + jj], a);
                hh[jj] = fmaxf(a, 0.f);
            }
            float* hp = hflat + ((size_t)(m*60 + n)*512 + o*32);
#pragma unroll
            for (int jj = 0; jj < 32; ++jj) {
                float a = s_bh2[jj];
#pragma unroll
                for (int i = 0; i < 32; ++i) a = fmaf(hh[i], s_wh2[i*32 + jj], a);
                hp[jj] = fmaxf(a, 0.f);
            }
        }
    }
}

// ---------------------------------------------------------------------------
// K2: fused logits GEMM + per-row argmax.  Grid (240 row-tiles, 59 col-tiles),
// 128x128 tile, 8x8 micro-tile/thread.  Lane map: row group = t>>4 (A-read is
// a 16-lane broadcast -> near-free LDS), col group = t&15.  Epilogue: per-row
// local argmax over 8 cols, 16-lane shfl_xor reduce, packed u64 atomicMax.
// ---------------------------------------------------------------------------
__global__ __launch_bounds__(256) void k2_logits_argmax(
    const float* __restrict__ hflat, const float* __restrict__ bpad,
    const float* __restrict__ b_cat, unsigned long long* __restrict__ keys)
{
    __shared__ __align__(16) float Alds[16*128];
    __shared__ __align__(16) float Blds[16*128];
    const int t = threadIdx.x;
    const int row0 = blockIdx.x * 128;
    const int col0 = blockIdx.y * 128;

    float acc[8][8];
#pragma unroll
    for (int i = 0; i < 8; ++i)
#pragma unroll
        for (int j = 0; j < 8; ++j) acc[i][j] = 0.f;

    const int arow = t >> 1;              // 0..127
    const int akq  = (t & 1) * 8;         // k half
    const int bk   = t >> 4;              // 0..15
    const int bc   = (t & 15) * 8;        // 0..120
    const float* Ag = hflat + (size_t)(row0 + arow) * 512 + akq;
    const float* Bg = bpad  + (size_t)bk * NPAD + col0 + bc;

    for (int kc = 0; kc < 32; ++kc) {
        __syncthreads();
        // stage A chunk (128 rows x 16 k), transposed to k-major
        const float4 a0 = *(const float4*)(Ag + kc*16);
        const float4 a1 = *(const float4*)(Ag + kc*16 + 4);
        Alds[(akq+0)*128 + arow] = a0.x;  Alds[(akq+1)*128 + arow] = a0.y;
        Alds[(akq+2)*128 + arow] = a0.z;  Alds[(akq+3)*128 + arow] = a0.w;
        Alds[(akq+4)*128 + arow] = a1.x;  Alds[(akq+5)*128 + arow] = a1.y;
        Alds[(akq+6)*128 + arow] = a1.z;  Alds[(akq+7)*128 + arow] = a1.w;
        // stage B chunk (16 k x 128 cols)
        const float4 v0 = *(const float4*)(Bg + (size_t)kc*16*NPAD);
        const float4 v1 = *(const float4*)(Bg + (size_t)kc*16*NPAD + 4);
        *(float4*)&Blds[bk*128 + bc]     = v0;
        *(float4*)&Blds[bk*128 + bc + 4] = v1;
        __syncthreads();

        const int r0 = (t >> 4) * 8, c0 = (t & 15) * 8;
#pragma unroll
        for (int k = 0; k < 16; ++k) {
            float a[8], b[8];
            *(float4*)&a[0] = *(const float4*)&Alds[k*128 + r0];
            *(float4*)&a[4] = *(const float4*)&Alds[k*128 + r0 + 4];
            *(float4*)&b[0] = *(const float4*)&Blds[k*128 + c0];
            *(float4*)&b[4] = *(const float4*)&Blds[k*128 + c0 + 4];
#pragma unroll
            for (int i = 0; i < 8; ++i)
#pragma unroll
                for (int j = 0; j < 8; ++j) acc[i][j] = fmaf(a[i], b[j], acc[i][j]);
        }
    }

    // epilogue: fused argmax
    const int r0  = (t >> 4) * 8;
    const int c0g = col0 + (t & 15) * 8;
#pragma unroll
    for (int i = 0; i < 8; ++i) {
        float bv = -__builtin_huge_valf();
        int   bi = 0x7FFFFFFF;
#pragma unroll
        for (int j = 0; j < 8; ++j) {
            const int col = c0g + j;
            if (col < NCLS) {
                const float v = acc[i][j] + b_cat[col];
                if (v > bv) { bv = v; bi = col; }    // ascending j + strict > => first-index ties
            }
        }
#pragma unroll
        for (int off = 1; off < 16; off <<= 1) {
            const float ov = __shfl_xor(bv, off, 64);
            const int   oi = __shfl_xor(bi, off, 64);
            if (ov > bv || (ov == bv && oi < bi)) { bv = ov; bi = oi; }
        }
        if ((t & 15) == 0)
            atomicMax(keys + row0 + r0 + i, packKey(bv, bi));
    }
}

// ---------------------------------------------------------------------------
// K3: rr1 = raw(512,15360) @ w_o1(15360,512), split-K x8 with fp32 atomicAdd.
// Grid (8 row-tiles, 8 col-tiles, 8 k-splits), 64x64 tile, 4x4 micro.
// ---------------------------------------------------------------------------
__global__ __launch_bounds__(256) void k3_rr1(
    const float* __restrict__ raw, const float* __restrict__ w_o1,
    float* __restrict__ rr1)
{
    __shared__ __align__(16) float Alds[16*64];
    __shared__ __align__(16) float Blds[16*64];
    const int t = threadIdx.x;
    const int row0 = blockIdx.x * 64;
    const int col0 = blockIdx.y * 64;
    const int ks   = blockIdx.z * 1920;

    float acc[4][4];
#pragma unroll
    for (int i = 0; i < 4; ++i)
#pragma unroll
        for (int j = 0; j < 4; ++j) acc[i][j] = 0.f;

    const int arow = t >> 2, akq = (t & 3) * 4;
    const int bk   = t >> 4, bc  = (t & 15) * 4;
    const float* Ag = raw  + (size_t)(row0 + arow) * RAWK + ks + akq;
    const float* Bg = w_o1 + (size_t)(ks + bk) * 512 + col0 + bc;

    for (int kc = 0; kc < 120; ++kc) {
        __syncthreads();
        const float4 a = *(const float4*)(Ag + kc*16);
        Alds[(akq+0)*64 + arow] = a.x;  Alds[(akq+1)*64 + arow] = a.y;
        Alds[(akq+2)*64 + arow] = a.z;  Alds[(akq+3)*64 + arow] = a.w;
        *(float4*)&Blds[bk*64 + bc] = *(const float4*)(Bg + (size_t)kc*16*512);
        __syncthreads();

        const int r0 = (t >> 4) * 4, c0 = (t & 15) * 4;
#pragma unroll
        for (int k = 0; k < 16; ++k) {
            float4 a4 = *(const float4*)&Alds[k*64 + r0];
            float4 b4 = *(const float4*)&Blds[k*64 + c0];
            acc[0][0]=fmaf(a4.x,b4.x,acc[0][0]); acc[0][1]=fmaf(a4.x,b4.y,acc[0][1]);
            acc[0][2]=fmaf(a4.x,b4.z,acc[0][2]); acc[0][3]=fmaf(a4.x,b4.w,acc[0][3]);
            acc[1][0]=fmaf(a4.y,b4.x,acc[1][0]); acc[1][1]=fmaf(a4.y,b4.y,acc[1][1]);
            acc[1][2]=fmaf(a4.y,b4.z,acc[1][2]); acc[1][3]=fmaf(a4.y,b4.w,acc[1][3]);
            acc[2][0]=fmaf(a4.z,b4.x,acc[2][0]); acc[2][1]=fmaf(a4.z,b4.y,acc[2][1]);
            acc[2][2]=fmaf(a4.z,b4.z,acc[2][2]); acc[2][3]=fmaf(a4.z,b4.w,acc[2][3]);
            acc[3][0]=fmaf(a4.w,b4.x,acc[3][0]); acc[3][1]=fmaf(a4.w,b4.y,acc[3][1]);
            acc[3][2]=fmaf(a4.w,b4.z,acc[3][2]); acc[3][3]=fmaf(a4.w,b4.w,acc[3][3]);
        }
    }
    const int r0 = (t >> 4) * 4, c0 = (t & 15) * 4;
#pragma unroll
    for (int i = 0; i < 4; ++i)
#pragma unroll
        for (int j = 0; j < 4; ++j)
            atomicAdd(&rr1[(size_t)(row0 + r0 + i)*512 + col0 + c0 + j], acc[i][j]);
}

// ---------------------------------------------------------------------------
// K4: per-m tail: relu(rr1+b_o1) -> rr2 -> rr3; best_hand = min over 60 keys;
//     final(128) @ w_sc -> out(512,6)
// ---------------------------------------------------------------------------
__global__ __launch_bounds__(256) void k4_tail(
    const float* __restrict__ rr1, const float* __restrict__ b_o1,
    const unsigned long long* __restrict__ keys,
    const float* __restrict__ w_o2, const float* __restrict__ b_o2,
    const float* __restrict__ w_o3, const float* __restrict__ b_o3,
    const float* __restrict__ w_sc, const float* __restrict__ b_sc,
    float* __restrict__ out)
{
    __shared__ float s1[512];
    __shared__ float s2[256];
    __shared__ float sf[128];
    __shared__ int s_best;
    const int t = threadIdx.x;
    const int m = blockIdx.x;

    if (t == 0) s_best = 0x7FFFFFFF;
    __syncthreads();
    for (int i = t; i < 512; i += 256)
        s1[i] = fmaxf(rr1[(size_t)m*512 + i] + b_o1[i], 0.f);
    if (t < 60) {
        const unsigned int cls = 0xFFFFFFFFu - (unsigned int)(keys[m*60 + t] & 0xFFFFFFFFull);
        atomicMin(&s_best, (int)cls);
    }
    __syncthreads();
    {
        float a = b_o2[t];
        for (int i = 0; i < 512; ++i) a = fmaf(s1[i], w_o2[i*256 + t], a);
        s2[t] = fmaxf(a, 0.f);
    }
    __syncthreads();
    if (t < 127) {
        float a = b_o3[t];
        for (int i = 0; i < 256; ++i) a = fmaf(s2[i], w_o3[i*127 + t], a);
        sf[t] = fmaxf(a, 0.f);
    }
    if (t == 0) sf[127] = (float)s_best;
    __syncthreads();
    if (t < 6) {
        float a = b_sc[t];
        for (int i = 0; i < 128; ++i) a = fmaf(sf[i], w_sc[i*6 + t], a);
        out[m*6 + t] = a;
    }
}

// ---------------------------------------------------------------------------
extern "C" void kernel_launch(void* const* d_in, const int* in_sizes, int n_in,
                              void* d_out, int out_size, void* d_ws, size_t ws_size,
                              hipStream_t stream)
{
    const int*   x       = (const int*)  d_in[0];
    const float* w_suit  = (const float*)d_in[1];
    const float* b_suit  = (const float*)d_in[2];
    const float* g_suit  = (const float*)d_in[3];
    const float* be_suit = (const float*)d_in[4];
    const float* w_rank  = (const float*)d_in[5];
    const float* b_rank  = (const float*)d_in[6];
    const float* g_rank  = (const float*)d_in[7];
    const float* be_rank = (const float*)d_in[8];
    const float* w_h1    = (const float*)d_in[9];
    const float* b_h1    = (const float*)d_in[10];
    const float* w_h2    = (const float*)d_in[11];
    const float* b_h2    = (const float*)d_in[12];
    const float* w_cat   = (const float*)d_in[13];
    const float* b_cat   = (const float*)d_in[14];
    const float* w_o1    = (const float*)d_in[15];
    const float* b_o1    = (const float*)d_in[16];
    const float* w_o2    = (const float*)d_in[17];
    const float* b_o2    = (const float*)d_in[18];
    const float* w_o3    = (const float*)d_in[19];
    const float* b_o3    = (const float*)d_in[20];
    const float* w_sc    = (const float*)d_in[21];
    const float* b_sc    = (const float*)d_in[22];
    float* out = (float*)d_out;

    char* ws = (char*)d_ws;
    float* raw   = (float*)(ws + OFF_RAW);
    float* hflat = (float*)(ws + OFF_HF);
    float* bpad  = (float*)(ws + OFF_BPAD);
    float* rr1   = (float*)(ws + OFF_RR1);
    unsigned long long* keys = (unsigned long long*)(ws + OFF_KEYS);

    hipMemsetAsync(rr1,  0, 512*512*sizeof(float), stream);
    hipMemsetAsync(keys, 0, 30720*sizeof(unsigned long long), stream);

    k0_bpad<<<dim3(30, 512), 256, 0, stream>>>(w_cat, bpad);
    k1_features<<<512, 256, 0, stream>>>(x, w_suit, b_suit, g_suit, be_suit,
                                         w_rank, b_rank, g_rank, be_rank,
                                         w_h1, b_h1, w_h2, b_h2, raw, hflat);
    k2_logits_argmax<<<dim3(240, 59), 256, 0, stream>>>(hflat, bpad, b_cat, keys);
    k3_rr1<<<dim3(8, 8, 8), 256, 0, stream>>>(raw, w_o1, rr1);
    k4_tail<<<512, 256, 0, stream>>>(rr1, b_o1, keys, w_o2, b_o2, w_o3, b_o3,
                                     w_sc, b_sc, out);
}

// Round 2
// 2444.667 us; speedup vs baseline: 1.2201x; 1.2201x over previous
//
#include <hip/hip_runtime.h>

// ---------------------------------------------------------------------------
// SmalldeckClassification on MI355X.
// Stage C (logits GEMM 30720x7463x512 + argmax) now runs on MFMA via bf16x3
// split (hi/lo), with per-tile top-2 tracking + fp32 fixup for near-tie rows
// so the argmax matches fp32 semantics.
// ---------------------------------------------------------------------------

typedef __attribute__((ext_vector_type(8))) short short8;
typedef __attribute__((ext_vector_type(8))) unsigned short ushort8;
typedef __attribute__((ext_vector_type(4))) float f32x4;

#define NCLS  7463
#define NPAD  7680         // 30 * 256
#define NTILE 30
#define RAWK  15360
#define TAU   0.01f

// ws layout (bytes)
#define OFF_RAW   0ull                 // 512*15360*4          = 31,457,280
#define OFF_A     31457280ull          // APACK 30720*2048     = 62,914,560
#define OFF_B     94371840ull          // BPACK 7680*2048      = 15,728,640
#define OFF_T2    110100480ull         // top2  30720*30*16    = 14,745,600
#define OFF_RR1   124846080ull         // 512*512*4            =  1,048,576
#define OFF_CLS   125894656ull         // 30720*4
#define OFF_LIST  126017536ull         // 30720*4
#define OFF_CNT   126140416ull         // 256

__device__ __constant__ signed char HC2[6][2] = {{0,1},{0,2},{0,3},{1,2},{1,3},{2,3}};
__device__ __constant__ signed char BC3[10][3] = {{4,5,6},{4,5,7},{4,5,8},{4,6,7},{4,6,8},
                                                  {4,7,8},{5,6,7},{5,6,8},{5,7,8},{6,7,8}};

__device__ __forceinline__ unsigned short f2bf(float x) {
    unsigned int u = __float_as_uint(x);
    unsigned int r = (u + 0x7fffu + ((u >> 16) & 1u)) >> 16;   // RNE
    return (unsigned short)r;
}
__device__ __forceinline__ float bf2f(unsigned short b) {
    return __uint_as_float(((unsigned int)b) << 16);
}

__device__ __forceinline__ void gl2lds16(const void* g, void* l) {
    __builtin_amdgcn_global_load_lds(
        (const __attribute__((address_space(1))) unsigned int*)g,
        (__attribute__((address_space(3))) unsigned int*)l, 16, 0, 0);
}

// ---------------------------------------------------------------------------
// K0: pack w_cat (512x7463) -> BPACK[col][kc8]{hi8,lo8} bf16, cols padded to 7680
// ---------------------------------------------------------------------------
__global__ __launch_bounds__(256) void k0_pack(const float* __restrict__ w_cat,
                                               char* __restrict__ bpack)
{
    const int t = threadIdx.x;
    const int col = blockIdx.x * 64 + (t & 63);
    const int kb  = blockIdx.y * 64 + (t >> 6) * 16;
    float vals[16];
#pragma unroll
    for (int i = 0; i < 16; ++i)
        vals[i] = (col < NCLS) ? w_cat[(size_t)(kb + i) * NCLS + col] : 0.f;
    char* rp = bpack + (size_t)col * 2048 + (size_t)(kb >> 3) * 32;
#pragma unroll
    for (int c = 0; c < 2; ++c) {
        ushort8 hi8, lo8;
#pragma unroll
        for (int j = 0; j < 8; ++j) {
            float x = vals[c * 8 + j];
            unsigned short hb = f2bf(x);
            float hf = bf2f(hb);
            unsigned short lb = f2bf(x - hf);
            hi8[j] = hb; lo8[j] = lb;
        }
        *(ushort8*)(rp + c * 32)      = hi8;
        *(ushort8*)(rp + c * 32 + 16) = lo8;
    }
}

// ---------------------------------------------------------------------------
// K1: per-m features -> raw (fp32) and APACK (hi/lo bf16 packed rows of 2048B)
// ---------------------------------------------------------------------------
__global__ __launch_bounds__(256) void k1_features(
    const int* __restrict__ x,
    const float* __restrict__ w_suit, const float* __restrict__ b_suit,
    const float* __restrict__ g_suit, const float* __restrict__ be_suit,
    const float* __restrict__ w_rank, const float* __restrict__ b_rank,
    const float* __restrict__ g_rank, const float* __restrict__ be_rank,
    const float* __restrict__ w_h1, const float* __restrict__ b_h1,
    const float* __restrict__ w_h2, const float* __restrict__ b_h2,
    float* __restrict__ raw, char* __restrict__ apack)
{
    __shared__ float s_wrank[400], s_wsuit[80];
    __shared__ float s_brank[16], s_bsuit[16];
    __shared__ float s_wh1[512], s_bh1[32], s_wh2[1024], s_bh2[32];
    __shared__ int   s_sr[9], s_ss[9];
    __shared__ float s_pr_sum[256], s_pr_sq[256], s_ps_sum[256], s_ps_sq[256];
    __shared__ float s_scale_r[16], s_shift_r[16], s_scale_s[16], s_shift_s[16];

    const int t = threadIdx.x;
    const int m = blockIdx.x;
    const int o = t & 15;

    for (int i = t; i < 400;  i += 256) s_wrank[i] = w_rank[i];
    for (int i = t; i < 80;   i += 256) s_wsuit[i] = w_suit[i];
    for (int i = t; i < 512;  i += 256) s_wh1[i]   = w_h1[i];
    for (int i = t; i < 1024; i += 256) s_wh2[i]   = w_h2[i];
    if (t < 16) { s_brank[t] = b_rank[t]; s_bsuit[t] = b_suit[t]; }
    if (t < 32) { s_bh1[t] = b_h1[t]; s_bh2[t] = b_h2[t]; }

    if (t == 0) {
        int r[9], s[9];
        for (int c = 0; c < 9; ++c) { r[c] = x[m*18 + 2*c]; s[c] = x[m*18 + 2*c + 1]; }
        for (int i = 1; i < 4; ++i) {
            int kr = r[i], ks = s[i], key = kr*16 + ks, j = i - 1;
            while (j >= 0 && (r[j]*16 + s[j]) > key) { r[j+1]=r[j]; s[j+1]=s[j]; --j; }
            r[j+1]=kr; s[j+1]=ks;
        }
        for (int i = 5; i < 9; ++i) {
            int kr = r[i], ks = s[i], key = kr*16 + ks, j = i - 1;
            while (j >= 4 && (r[j]*16 + s[j]) > key) { r[j+1]=r[j]; s[j+1]=s[j]; --j; }
            r[j+1]=kr; s[j+1]=ks;
        }
        for (int c = 0; c < 9; ++c) { s_sr[c] = r[c]; s_ss[c] = s[c]; }
    }
    __syncthreads();

    float rv[4][11], sv[4][5];
    float pr_sum = 0.f, pr_sq = 0.f, ps_sum = 0.f, ps_sq = 0.f;
#pragma unroll
    for (int u = 0; u < 4; ++u) {
        const int p = t + u*256;
        if (p < 960) {
            const int n = p >> 4;
            const int hi = n / 10, bi = n % 10;
            int cr[5], cs[5];
            cr[0] = s_sr[HC2[hi][0]]; cs[0] = s_ss[HC2[hi][0]];
            cr[1] = s_sr[HC2[hi][1]]; cs[1] = s_ss[HC2[hi][1]];
            cr[2] = s_sr[BC3[bi][0]]; cs[2] = s_ss[BC3[bi][0]];
            cr[3] = s_sr[BC3[bi][1]]; cs[3] = s_ss[BC3[bi][1]];
            cr[4] = s_sr[BC3[bi][2]]; cs[4] = s_ss[BC3[bi][2]];
            const float br = s_brank[o];
#pragma unroll
            for (int j = 0; j < 11; ++j) {
                float v = br;
#pragma unroll
                for (int c = 0; c < 5; ++c) {
                    const int k = cr[c] - j;
                    if (k >= 0 && k < 5) v += s_wrank[(o*5 + c)*5 + k];
                }
                rv[u][j] = v; pr_sum += v; pr_sq += v*v;
            }
            const float bs = s_bsuit[o];
#pragma unroll
            for (int l = 0; l < 5; ++l) {
                float v = bs;
#pragma unroll
                for (int c = 0; c < 5; ++c) if (cs[c] == l) v += s_wsuit[o*5 + c];
                sv[u][l] = v; ps_sum += v; ps_sq += v*v;
            }
        } else {
#pragma unroll
            for (int j = 0; j < 11; ++j) rv[u][j] = 0.f;
#pragma unroll
            for (int l = 0; l < 5; ++l)  sv[u][l] = 0.f;
        }
    }
    s_pr_sum[t] = pr_sum; s_pr_sq[t] = pr_sq; s_ps_sum[t] = ps_sum; s_ps_sq[t] = ps_sq;
    __syncthreads();

    if (t < 16) {
        float sr = 0.f, sqr = 0.f, ss2 = 0.f, sqs = 0.f;
        for (int slot = 0; slot < 16; ++slot) {
            sr  += s_pr_sum[slot*16 + t];
            sqr += s_pr_sq [slot*16 + t];
            ss2 += s_ps_sum[slot*16 + t];
            sqs += s_ps_sq [slot*16 + t];
        }
        const float nr = 1.f / 660.f, ns = 1.f / 300.f;
        const float mr = sr * nr,  varr = sqr * nr - mr*mr;
        const float ms = ss2 * ns, vars = sqs * ns - ms*ms;
        const float scr = g_rank[t] * rsqrtf(varr + 1e-5f);
        const float scs = g_suit[t] * rsqrtf(vars + 1e-5f);
        s_scale_r[t] = scr; s_shift_r[t] = be_rank[t] - mr * scr;
        s_scale_s[t] = scs; s_shift_s[t] = be_suit[t] - ms * scs;
    }
    __syncthreads();

    const float sc_r = s_scale_r[o], sh_r = s_shift_r[o];
    const float sc_s = s_scale_s[o], sh_s = s_shift_s[o];
#pragma unroll
    for (int u = 0; u < 4; ++u) {
        const int p = t + u*256;
        if (p < 960) {
            const int n = p >> 4;
            float v[16];
#pragma unroll
            for (int j = 0; j < 11; ++j) v[j]    = fmaxf(rv[u][j]*sc_r + sh_r, 0.f);
#pragma unroll
            for (int l = 0; l < 5; ++l)  v[11+l] = fmaxf(sv[u][l]*sc_s + sh_s, 0.f);
            float* rawp = raw + ((size_t)m*15360 + n*256 + o*16);
#pragma unroll
            for (int j = 0; j < 16; ++j) rawp[j] = v[j];
            float hh[32];
#pragma unroll
            for (int jj = 0; jj < 32; ++jj) {
                float a = s_bh1[jj];
#pragma unroll
                for (int i = 0; i < 16; ++i) a = fmaf(v[i], s_wh1[i*32 + jj], a);
                hh[jj] = fmaxf(a, 0.f);
            }
            // h2 + bf16 hi/lo pack: k range o*32..o*32+31 -> 4 chunk pairs
            char* rowp = apack + (size_t)(m*60 + n) * 2048 + o * 128;
#pragma unroll
            for (int c4 = 0; c4 < 4; ++c4) {
                ushort8 hi8, lo8;
#pragma unroll
                for (int j = 0; j < 8; ++j) {
                    const int jj = c4*8 + j;
                    float a = s_bh2[jj];
#pragma unroll
                    for (int i = 0; i < 32; ++i) a = fmaf(hh[i], s_wh2[i*32 + jj], a);
                    float xv = fmaxf(a, 0.f);
                    unsigned short hb = f2bf(xv);
                    float hf = bf2f(hb);
                    unsigned short lb = f2bf(xv - hf);
                    hi8[j] = hb; lo8[j] = lb;
                }
                *(ushort8*)(rowp + c4*32)      = hi8;
                *(ushort8*)(rowp + c4*32 + 16) = lo8;
            }
        }
    }
}

// ---------------------------------------------------------------------------
// K2: bf16x3 MFMA logits + per-(row, col-tile) top2.
// 128x256 tile, 4 waves (64x128 each), BK=32, hi/lo interleaved LDS rows of
// 128B with (row&7)<<4 XOR swizzle; staged via global_load_lds w/ pre-swizzled
// global source. Grid: 7200 blocks, XCD-swizzled.
// ---------------------------------------------------------------------------
__global__ __launch_bounds__(256, 2) void k2_mfma(
    const char* __restrict__ apack, const char* __restrict__ bpack,
    const float* __restrict__ b_cat, uint4* __restrict__ top2buf)
{
    __shared__ __align__(16) unsigned char s_lds[49152];   // A 16KB | B 32KB
    const int t = threadIdx.x;
    const int lane = t & 63;
    const int w  = t >> 6;
    const int wr = w >> 1, wc = w & 1;

    const int bid = blockIdx.x;
    const int swz = (bid & 7) * 900 + (bid >> 3);
    const int brow = swz % 240, bcol = swz / 240;
    const int row0 = brow * 128;
    const int col0 = bcol * 256;

    // staging pointers (chunk c = i*256 + t; row=c>>3, slot=c&7; src slot pre-XORed)
    const char* aSrc[4]; const char* bSrc[8];
    unsigned char* aDst[4]; unsigned char* bDst[8];
#pragma unroll
    for (int i = 0; i < 4; ++i) {
        const int c = i*256 + t, r = c >> 3, s = c & 7;
        aSrc[i] = apack + (size_t)(row0 + r) * 2048 + ((s ^ (r & 7)) << 4);
        aDst[i] = &s_lds[(i*256 + (t & 192)) * 16];
    }
#pragma unroll
    for (int i = 0; i < 8; ++i) {
        const int c = i*256 + t, r = c >> 3, s = c & 7;
        bSrc[i] = bpack + (size_t)(col0 + r) * 2048 + ((s ^ (r & 7)) << 4);
        bDst[i] = &s_lds[16384 + (i*256 + (t & 192)) * 16];
    }

    f32x4 acc[4][8] = {};

    for (int it = 0; it < 16; ++it) {
#pragma unroll
        for (int i = 0; i < 4; ++i) gl2lds16(aSrc[i] + it*128, aDst[i]);
#pragma unroll
        for (int i = 0; i < 8; ++i) gl2lds16(bSrc[i] + it*128, bDst[i]);
        __syncthreads();          // drains vmcnt before barrier -> LDS ready

        short8 ah[4], al[4];
#pragma unroll
        for (int fr = 0; fr < 4; ++fr) {
            const int row = wr*64 + fr*16 + (lane & 15);
            const int base = row*128 + (((lane >> 4) * 32) ^ ((row & 7) << 4));
            ah[fr] = *(const short8*)&s_lds[base];
            al[fr] = *(const short8*)&s_lds[base ^ 16];
        }
#pragma unroll
        for (int fc = 0; fc < 8; ++fc) {
            const int col = wc*128 + fc*16 + (lane & 15);
            const int base = 16384 + col*128 + (((lane >> 4) * 32) ^ ((col & 7) << 4));
            const short8 bh = *(const short8*)&s_lds[base];
            const short8 bl = *(const short8*)&s_lds[base ^ 16];
#pragma unroll
            for (int fr = 0; fr < 4; ++fr)
                acc[fr][fc] = __builtin_amdgcn_mfma_f32_16x16x32_bf16(ah[fr], bh, acc[fr][fc], 0, 0, 0);
#pragma unroll
            for (int fr = 0; fr < 4; ++fr)
                acc[fr][fc] = __builtin_amdgcn_mfma_f32_16x16x32_bf16(al[fr], bh, acc[fr][fc], 0, 0, 0);
#pragma unroll
            for (int fr = 0; fr < 4; ++fr)
                acc[fr][fc] = __builtin_amdgcn_mfma_f32_16x16x32_bf16(ah[fr], bl, acc[fr][fc], 0, 0, 0);
        }
        __syncthreads();
    }

    // ---- epilogue: per-row top2 over this block's 256 cols ----
    uint4* sm = (uint4*)s_lds;   // [128 rows][2 wc]
#pragma unroll
    for (int fr = 0; fr < 4; ++fr) {
#pragma unroll
        for (int reg = 0; reg < 4; ++reg) {
            float v1 = -3.0e38f, v2 = -3.0e38f;
            int   i1 = 0x7fffffff, i2 = 0x7fffffff;
#pragma unroll
            for (int fc = 0; fc < 8; ++fc) {
                const int colg = col0 + wc*128 + fc*16 + (lane & 15);
                const float v = (colg < NCLS) ? (acc[fr][fc][reg] + b_cat[colg]) : -3.0e38f;
                if (v > v1 || (v == v1 && colg < i1)) { v2=v1; i2=i1; v1=v; i1=colg; }
                else if (v > v2 || (v == v2 && colg < i2)) { v2=v; i2=colg; }
            }
#pragma unroll
            for (int off = 1; off < 16; off <<= 1) {
                const float w1 = __shfl_xor(v1, off, 64); const int j1 = __shfl_xor(i1, off, 64);
                const float w2 = __shfl_xor(v2, off, 64); const int j2 = __shfl_xor(i2, off, 64);
                if (w1 > v1 || (w1 == v1 && j1 < i1)) { v2=v1; i2=i1; v1=w1; i1=j1; }
                else if (w1 > v2 || (w1 == v2 && j1 < i2)) { v2=w1; i2=j1; }
                if (w2 > v1 || (w2 == v1 && j2 < i1)) { v2=v1; i2=i1; v1=w2; i1=j2; }
                else if (w2 > v2 || (w2 == v2 && j2 < i2)) { v2=w2; i2=j2; }
            }
            if ((lane & 15) == 0) {
                const int rl = wr*64 + fr*16 + (lane >> 4)*4 + reg;
                sm[rl*2 + wc] = make_uint4(__float_as_uint(v1), (unsigned)i1,
                                           __float_as_uint(v2), (unsigned)i2);
            }
        }
    }
    __syncthreads();
    if (t < 128) {
        const uint4 e0 = sm[t*2], e1 = sm[t*2 + 1];
        float v1 = __uint_as_float(e0.x); int i1 = (int)e0.y;
        float v2 = __uint_as_float(e0.z); int i2 = (int)e0.w;
        const float w1 = __uint_as_float(e1.x); const int j1 = (int)e1.y;
        const float w2 = __uint_as_float(e1.z); const int j2 = (int)e1.w;
        if (w1 > v1 || (w1 == v1 && j1 < i1)) { v2=v1; i2=i1; v1=w1; i1=j1; }
        else if (w1 > v2 || (w1 == v2 && j1 < i2)) { v2=w1; i2=j1; }
        if (w2 > v1 || (w2 == v1 && j2 < i1)) { v2=v1; i2=i1; v1=w2; i1=j2; }
        else if (w2 > v2 || (w2 == v2 && j2 < i2)) { v2=w2; i2=j2; }
        top2buf[(size_t)(row0 + t) * NTILE + bcol] =
            make_uint4(__float_as_uint(v1), (unsigned)i1, __float_as_uint(v2), (unsigned)i2);
    }
}

// ---------------------------------------------------------------------------
// K2b: reduce 30 tiles/row -> cls + near-tie fixup list
// ---------------------------------------------------------------------------
__global__ __launch_bounds__(256) void k2b_reduce(
    const uint4* __restrict__ top2buf, unsigned int* __restrict__ cls,
    unsigned int* __restrict__ list, unsigned int* __restrict__ cnt)
{
    const int row = blockIdx.x * 256 + threadIdx.x;
    float v1 = -3.0e38f, v2 = -3.0e38f;
    int   i1 = 0x7fffffff, i2 = 0x7fffffff;
    for (int tc = 0; tc < NTILE; ++tc) {
        const uint4 e = top2buf[(size_t)row * NTILE + tc];
        const float a1 = __uint_as_float(e.x); const int b1 = (int)e.y;
        const float a2 = __uint_as_float(e.z); const int b2 = (int)e.w;
        if (a1 > v1 || (a1 == v1 && b1 < i1)) { v2=v1; i2=i1; v1=a1; i1=b1; }
        else if (a1 > v2 || (a1 == v2 && b1 < i2)) { v2=a1; i2=b1; }
        if (a2 > v1 || (a2 == v1 && b2 < i1)) { v2=v1; i2=i1; v1=a2; i1=b2; }
        else if (a2 > v2 || (a2 == v2 && b2 < i2)) { v2=a2; i2=b2; }
    }
    cls[row] = (unsigned)i1;
    if (v1 - v2 <= TAU) {
        const unsigned s = atomicAdd(cnt, 1u);
        list[s] = (unsigned)row;
    }
}

// ---------------------------------------------------------------------------
// K2c: fp32 recompute of the 60 per-tile candidates for flagged rows
// ---------------------------------------------------------------------------
__global__ __launch_bounds__(256) void k2c_fixup(
    const char* __restrict__ apack, const char* __restrict__ bpack,
    const float* __restrict__ b_cat, const uint4* __restrict__ top2buf,
    const unsigned int* __restrict__ list, const unsigned int* __restrict__ cnt,
    unsigned int* __restrict__ cls)
{
    __shared__ float h[512];
    __shared__ float s_bv[4];
    __shared__ int   s_bi[4];
    const int t = threadIdx.x, lane = t & 63, wid = t >> 6;
    const int n = (int)*cnt;
    for (int idx = blockIdx.x; idx < n; idx += gridDim.x) {
        const int row = (int)list[idx];
        __syncthreads();
        if (t < 64) {
            const ushort8 hi = *(const ushort8*)(apack + (size_t)row*2048 + t*32);
            const ushort8 lo = *(const ushort8*)(apack + (size_t)row*2048 + t*32 + 16);
#pragma unroll
            for (int j = 0; j < 8; ++j) h[t*8 + j] = bf2f(hi[j]) + bf2f(lo[j]);
        }
        __syncthreads();
        float bv = -3.0e38f; int bi = 0x7fffffff;
        for (int c = wid; c < 60; c += 4) {
            const uint4 e = top2buf[(size_t)row * NTILE + (c >> 1)];
            const int colc = (c & 1) ? (int)e.w : (int)e.y;
            const ushort8 bh = *(const ushort8*)(bpack + (size_t)colc*2048 + lane*32);
            const ushort8 bl = *(const ushort8*)(bpack + (size_t)colc*2048 + lane*32 + 16);
            float p = 0.f;
#pragma unroll
            for (int j = 0; j < 8; ++j) p += h[lane*8 + j] * (bf2f(bh[j]) + bf2f(bl[j]));
#pragma unroll
            for (int off = 1; off < 64; off <<= 1) p += __shfl_xor(p, off, 64);
            const float v = p + b_cat[colc];
            if (v > bv || (v == bv && colc < bi)) { bv = v; bi = colc; }
        }
        if (lane == 0) { s_bv[wid] = bv; s_bi[wid] = bi; }
        __syncthreads();
        if (t == 0) {
            float V = s_bv[0]; int I = s_bi[0];
#pragma unroll
            for (int wv = 1; wv < 4; ++wv)
                if (s_bv[wv] > V || (s_bv[wv] == V && s_bi[wv] < I)) { V = s_bv[wv]; I = s_bi[wv]; }
            cls[row] = (unsigned)I;
        }
    }
}

// ---------------------------------------------------------------------------
// K3: rr1 = raw(512,15360) @ w_o1(15360,512), split-K x8 fp32 atomicAdd
// ---------------------------------------------------------------------------
__global__ __launch_bounds__(256) void k3_rr1(
    const float* __restrict__ raw, const float* __restrict__ w_o1,
    float* __restrict__ rr1)
{
    __shared__ __align__(16) float Alds[16*64];
    __shared__ __align__(16) float Blds[16*64];
    const int t = threadIdx.x;
    const int row0 = blockIdx.x * 64;
    const int col0 = blockIdx.y * 64;
    const int ks   = blockIdx.z * 1920;

    float acc[4][4];
#pragma unroll
    for (int i = 0; i < 4; ++i)
#pragma unroll
        for (int j = 0; j < 4; ++j) acc[i][j] = 0.f;

    const int arow = t >> 2, akq = (t & 3) * 4;
    const int bk   = t >> 4, bc  = (t & 15) * 4;
    const float* Ag = raw  + (size_t)(row0 + arow) * RAWK + ks + akq;
    const float* Bg = w_o1 + (size_t)(ks + bk) * 512 + col0 + bc;

    for (int kc = 0; kc < 120; ++kc) {
        __syncthreads();
        const float4 a = *(const float4*)(Ag + kc*16);
        Alds[(akq+0)*64 + arow] = a.x;  Alds[(akq+1)*64 + arow] = a.y;
        Alds[(akq+2)*64 + arow] = a.z;  Alds[(akq+3)*64 + arow] = a.w;
        *(float4*)&Blds[bk*64 + bc] = *(const float4*)(Bg + (size_t)kc*16*512);
        __syncthreads();

        const int r0 = (t >> 4) * 4, c0 = (t & 15) * 4;
#pragma unroll
        for (int k = 0; k < 16; ++k) {
            float4 a4 = *(const float4*)&Alds[k*64 + r0];
            float4 b4 = *(const float4*)&Blds[k*64 + c0];
            acc[0][0]=fmaf(a4.x,b4.x,acc[0][0]); acc[0][1]=fmaf(a4.x,b4.y,acc[0][1]);
            acc[0][2]=fmaf(a4.x,b4.z,acc[0][2]); acc[0][3]=fmaf(a4.x,b4.w,acc[0][3]);
            acc[1][0]=fmaf(a4.y,b4.x,acc[1][0]); acc[1][1]=fmaf(a4.y,b4.y,acc[1][1]);
            acc[1][2]=fmaf(a4.y,b4.z,acc[1][2]); acc[1][3]=fmaf(a4.y,b4.w,acc[1][3]);
            acc[2][0]=fmaf(a4.z,b4.x,acc[2][0]); acc[2][1]=fmaf(a4.z,b4.y,acc[2][1]);
            acc[2][2]=fmaf(a4.z,b4.z,acc[2][2]); acc[2][3]=fmaf(a4.z,b4.w,acc[2][3]);
            acc[3][0]=fmaf(a4.w,b4.x,acc[3][0]); acc[3][1]=fmaf(a4.w,b4.y,acc[3][1]);
            acc[3][2]=fmaf(a4.w,b4.z,acc[3][2]); acc[3][3]=fmaf(a4.w,b4.w,acc[3][3]);
        }
    }
    const int r0 = (t >> 4) * 4, c0 = (t & 15) * 4;
#pragma unroll
    for (int i = 0; i < 4; ++i)
#pragma unroll
        for (int j = 0; j < 4; ++j)
            atomicAdd(&rr1[(size_t)(row0 + r0 + i)*512 + col0 + c0 + j], acc[i][j]);
}

// ---------------------------------------------------------------------------
// K4: per-m tail + best_hand(min of cls over 60) + final @ w_sc
// ---------------------------------------------------------------------------
__global__ __launch_bounds__(256) void k4_tail(
    const float* __restrict__ rr1, const float* __restrict__ b_o1,
    const unsigned int* __restrict__ cls,
    const float* __restrict__ w_o2, const float* __restrict__ b_o2,
    const float* __restrict__ w_o3, const float* __restrict__ b_o3,
    const float* __restrict__ w_sc, const float* __restrict__ b_sc,
    float* __restrict__ out)
{
    __shared__ float s1[512];
    __shared__ float s2[256];
    __shared__ float sf[128];
    __shared__ int s_best;
    const int t = threadIdx.x;
    const int m = blockIdx.x;

    if (t == 0) s_best = 0x7FFFFFFF;
    __syncthreads();
    for (int i = t; i < 512; i += 256)
        s1[i] = fmaxf(rr1[(size_t)m*512 + i] + b_o1[i], 0.f);
    if (t < 60) atomicMin(&s_best, (int)cls[m*60 + t]);
    __syncthreads();
    {
        float a = b_o2[t];
        for (int i = 0; i < 512; ++i) a = fmaf(s1[i], w_o2[i*256 + t], a);
        s2[t] = fmaxf(a, 0.f);
    }
    __syncthreads();
    if (t < 127) {
        float a = b_o3[t];
        for (int i = 0; i < 256; ++i) a = fmaf(s2[i], w_o3[i*127 + t], a);
        sf[t] = fmaxf(a, 0.f);
    }
    if (t == 0) sf[127] = (float)s_best;
    __syncthreads();
    if (t < 6) {
        float a = b_sc[t];
        for (int i = 0; i < 128; ++i) a = fmaf(sf[i], w_sc[i*6 + t], a);
        out[m*6 + t] = a;
    }
}

// ---------------------------------------------------------------------------
extern "C" void kernel_launch(void* const* d_in, const int* in_sizes, int n_in,
                              void* d_out, int out_size, void* d_ws, size_t ws_size,
                              hipStream_t stream)
{
    const int*   x       = (const int*)  d_in[0];
    const float* w_suit  = (const float*)d_in[1];
    const float* b_suit  = (const float*)d_in[2];
    const float* g_suit  = (const float*)d_in[3];
    const float* be_suit = (const float*)d_in[4];
    const float* w_rank  = (const float*)d_in[5];
    const float* b_rank  = (const float*)d_in[6];
    const float* g_rank  = (const float*)d_in[7];
    const float* be_rank = (const float*)d_in[8];
    const float* w_h1    = (const float*)d_in[9];
    const float* b_h1    = (const float*)d_in[10];
    const float* w_h2    = (const float*)d_in[11];
    const float* b_h2    = (const float*)d_in[12];
    const float* w_cat   = (const float*)d_in[13];
    const float* b_cat   = (const float*)d_in[14];
    const float* w_o1    = (const float*)d_in[15];
    const float* b_o1    = (const float*)d_in[16];
    const float* w_o2    = (const float*)d_in[17];
    const float* b_o2    = (const float*)d_in[18];
    const float* w_o3    = (const float*)d_in[19];
    const float* b_o3    = (const float*)d_in[20];
    const float* w_sc    = (const float*)d_in[21];
    const float* b_sc    = (const float*)d_in[22];
    float* out = (float*)d_out;

    char* ws = (char*)d_ws;
    float* raw   = (float*)(ws + OFF_RAW);
    char*  apack = ws + OFF_A;
    char*  bpack = ws + OFF_B;
    uint4* top2  = (uint4*)(ws + OFF_T2);
    float* rr1   = (float*)(ws + OFF_RR1);
    unsigned int* cls  = (unsigned int*)(ws + OFF_CLS);
    unsigned int* list = (unsigned int*)(ws + OFF_LIST);
    unsigned int* cnt  = (unsigned int*)(ws + OFF_CNT);

    hipMemsetAsync(rr1, 0, 512*512*sizeof(float), stream);
    hipMemsetAsync(cnt, 0, 256, stream);

    k0_pack<<<dim3(120, 8), 256, 0, stream>>>(w_cat, bpack);
    k1_features<<<512, 256, 0, stream>>>(x, w_suit, b_suit, g_suit, be_suit,
                                         w_rank, b_rank, g_rank, be_rank,
                                         w_h1, b_h1, w_h2, b_h2, raw, apack);
    k2_mfma<<<7200, 256, 0, stream>>>(apack, bpack, b_cat, top2);
    k2b_reduce<<<120, 256, 0, stream>>>(top2, cls, list, cnt);
    k2c_fixup<<<240, 256, 0, stream>>>(apack, bpack, b_cat, top2, list, cnt, cls);
    k3_rr1<<<dim3(8, 8, 8), 256, 0, stream>>>(raw, w_o1, rr1);
    k4_tail<<<512, 256, 0, stream>>>(rr1, b_o1, cls, w_o2, b_o2, w_o3, b_o3,
                                     w_sc, b_sc, out);
}

// Round 4
// 1700.916 us; speedup vs baseline: 1.7537x; 1.4373x over previous
//
#include <hip/hip_runtime.h>

// ---------------------------------------------------------------------------
// SmalldeckClassification on MI355X.
// k2: bf16x3 MFMA logits GEMM, 256x256 tile, 8 waves, 2-phase double-buffered
//     LDS pipeline (T3-minimum template), fused per-tile top-2.
//     LDS is STATIC 128 KiB (dynamic >64KB requires runtime opt-in and kills
//     graph capture -- R3 container failure).
// k2b: tile-reduce + near-tie flag (tau=2e-4, calibrated to bf16x3 err ~1e-5).
// k2c: parallel fp32 fixup (1024 blocks).
// ---------------------------------------------------------------------------

typedef __attribute__((ext_vector_type(8))) short short8;
typedef __attribute__((ext_vector_type(8))) unsigned short ushort8;
typedef __attribute__((ext_vector_type(4))) float f32x4;

#define NCLS  7463
#define NPAD  7680         // 30 * 256
#define NTILE 30
#define RAWK  15360
#define TAU   2.0e-4f

// ws layout (bytes)
#define OFF_RAW   0ull                 // 512*15360*4          = 31,457,280
#define OFF_A     31457280ull          // APACK 30720*2048     = 62,914,560
#define OFF_B     94371840ull          // BPACK 7680*2048      = 15,728,640
#define OFF_T2    110100480ull         // top2  30720*30*16    = 14,745,600
#define OFF_RR1   124846080ull         // 512*512*4            =  1,048,576
#define OFF_CLS   125894656ull         // 30720*4
#define OFF_LIST  126017536ull         // 30720*4
#define OFF_CNT   126140416ull         // 256

__device__ __constant__ signed char HC2[6][2] = {{0,1},{0,2},{0,3},{1,2},{1,3},{2,3}};
__device__ __constant__ signed char BC3[10][3] = {{4,5,6},{4,5,7},{4,5,8},{4,6,7},{4,6,8},
                                                  {4,7,8},{5,6,7},{5,6,8},{5,7,8},{6,7,8}};

__device__ __forceinline__ unsigned short f2bf(float x) {
    unsigned int u = __float_as_uint(x);
    unsigned int r = (u + 0x7fffu + ((u >> 16) & 1u)) >> 16;   // RNE
    return (unsigned short)r;
}
__device__ __forceinline__ float bf2f(unsigned short b) {
    return __uint_as_float(((unsigned int)b) << 16);
}

__device__ __forceinline__ void gl2lds16(const void* g, void* l) {
    __builtin_amdgcn_global_load_lds(
        (const __attribute__((address_space(1))) unsigned int*)g,
        (__attribute__((address_space(3))) unsigned int*)l, 16, 0, 0);
}

// ---------------------------------------------------------------------------
// K0: pack w_cat (512x7463) -> BPACK[col][kc8]{hi8,lo8} bf16, cols padded 7680
// ---------------------------------------------------------------------------
__global__ __launch_bounds__(256) void k0_pack(const float* __restrict__ w_cat,
                                               char* __restrict__ bpack)
{
    const int t = threadIdx.x;
    const int col = blockIdx.x * 64 + (t & 63);
    const int kb  = blockIdx.y * 64 + (t >> 6) * 16;
    float vals[16];
#pragma unroll
    for (int i = 0; i < 16; ++i)
        vals[i] = (col < NCLS) ? w_cat[(size_t)(kb + i) * NCLS + col] : 0.f;
    char* rp = bpack + (size_t)col * 2048 + (size_t)(kb >> 3) * 32;
#pragma unroll
    for (int c = 0; c < 2; ++c) {
        ushort8 hi8, lo8;
#pragma unroll
        for (int j = 0; j < 8; ++j) {
            float x = vals[c * 8 + j];
            unsigned short hb = f2bf(x);
            float hf = bf2f(hb);
            unsigned short lb = f2bf(x - hf);
            hi8[j] = hb; lo8[j] = lb;
        }
        *(ushort8*)(rp + c * 32)      = hi8;
        *(ushort8*)(rp + c * 32 + 16) = lo8;
    }
}

// ---------------------------------------------------------------------------
// K1: per-m features -> raw (fp32) and APACK (hi/lo bf16 packed rows of 2048B)
// ---------------------------------------------------------------------------
__global__ __launch_bounds__(256) void k1_features(
    const int* __restrict__ x,
    const float* __restrict__ w_suit, const float* __restrict__ b_suit,
    const float* __restrict__ g_suit, const float* __restrict__ be_suit,
    const float* __restrict__ w_rank, const float* __restrict__ b_rank,
    const float* __restrict__ g_rank, const float* __restrict__ be_rank,
    const float* __restrict__ w_h1, const float* __restrict__ b_h1,
    const float* __restrict__ w_h2, const float* __restrict__ b_h2,
    float* __restrict__ raw, char* __restrict__ apack)
{
    __shared__ float s_wrank[400], s_wsuit[80];
    __shared__ float s_brank[16], s_bsuit[16];
    __shared__ float s_wh1[512], s_bh1[32], s_wh2[1024], s_bh2[32];
    __shared__ int   s_sr[9], s_ss[9];
    __shared__ float s_pr_sum[256], s_pr_sq[256], s_ps_sum[256], s_ps_sq[256];
    __shared__ float s_scale_r[16], s_shift_r[16], s_scale_s[16], s_shift_s[16];

    const int t = threadIdx.x;
    const int m = blockIdx.x;
    const int o = t & 15;

    for (int i = t; i < 400;  i += 256) s_wrank[i] = w_rank[i];
    for (int i = t; i < 80;   i += 256) s_wsuit[i] = w_suit[i];
    for (int i = t; i < 512;  i += 256) s_wh1[i]   = w_h1[i];
    for (int i = t; i < 1024; i += 256) s_wh2[i]   = w_h2[i];
    if (t < 16) { s_brank[t] = b_rank[t]; s_bsuit[t] = b_suit[t]; }
    if (t < 32) { s_bh1[t] = b_h1[t]; s_bh2[t] = b_h2[t]; }

    if (t == 0) {
        int r[9], s[9];
        for (int c = 0; c < 9; ++c) { r[c] = x[m*18 + 2*c]; s[c] = x[m*18 + 2*c + 1]; }
        for (int i = 1; i < 4; ++i) {
            int kr = r[i], ks = s[i], key = kr*16 + ks, j = i - 1;
            while (j >= 0 && (r[j]*16 + s[j]) > key) { r[j+1]=r[j]; s[j+1]=s[j]; --j; }
            r[j+1]=kr; s[j+1]=ks;
        }
        for (int i = 5; i < 9; ++i) {
            int kr = r[i], ks = s[i], key = kr*16 + ks, j = i - 1;
            while (j >= 4 && (r[j]*16 + s[j]) > key) { r[j+1]=r[j]; s[j+1]=s[j]; --j; }
            r[j+1]=kr; s[j+1]=ks;
        }
        for (int c = 0; c < 9; ++c) { s_sr[c] = r[c]; s_ss[c] = s[c]; }
    }
    __syncthreads();

    float rv[4][11], sv[4][5];
    float pr_sum = 0.f, pr_sq = 0.f, ps_sum = 0.f, ps_sq = 0.f;
#pragma unroll
    for (int u = 0; u < 4; ++u) {
        const int p = t + u*256;
        if (p < 960) {
            const int n = p >> 4;
            const int hi = n / 10, bi = n % 10;
            int cr[5], cs[5];
            cr[0] = s_sr[HC2[hi][0]]; cs[0] = s_ss[HC2[hi][0]];
            cr[1] = s_sr[HC2[hi][1]]; cs[1] = s_ss[HC2[hi][1]];
            cr[2] = s_sr[BC3[bi][0]]; cs[2] = s_ss[BC3[bi][0]];
            cr[3] = s_sr[BC3[bi][1]]; cs[3] = s_ss[BC3[bi][1]];
            cr[4] = s_sr[BC3[bi][2]]; cs[4] = s_ss[BC3[bi][2]];
            const float br = s_brank[o];
#pragma unroll
            for (int j = 0; j < 11; ++j) {
                float v = br;
#pragma unroll
                for (int c = 0; c < 5; ++c) {
                    const int k = cr[c] - j;
                    if (k >= 0 && k < 5) v += s_wrank[(o*5 + c)*5 + k];
                }
                rv[u][j] = v; pr_sum += v; pr_sq += v*v;
            }
            const float bs = s_bsuit[o];
#pragma unroll
            for (int l = 0; l < 5; ++l) {
                float v = bs;
#pragma unroll
                for (int c = 0; c < 5; ++c) if (cs[c] == l) v += s_wsuit[o*5 + c];
                sv[u][l] = v; ps_sum += v; ps_sq += v*v;
            }
        } else {
#pragma unroll
            for (int j = 0; j < 11; ++j) rv[u][j] = 0.f;
#pragma unroll
            for (int l = 0; l < 5; ++l)  sv[u][l] = 0.f;
        }
    }
    s_pr_sum[t] = pr_sum; s_pr_sq[t] = pr_sq; s_ps_sum[t] = ps_sum; s_ps_sq[t] = ps_sq;
    __syncthreads();

    if (t < 16) {
        float sr = 0.f, sqr = 0.f, ss2 = 0.f, sqs = 0.f;
        for (int slot = 0; slot < 16; ++slot) {
            sr  += s_pr_sum[slot*16 + t];
            sqr += s_pr_sq [slot*16 + t];
            ss2 += s_ps_sum[slot*16 + t];
            sqs += s_ps_sq [slot*16 + t];
        }
        const float nr = 1.f / 660.f, ns = 1.f / 300.f;
        const float mr = sr * nr,  varr = sqr * nr - mr*mr;
        const float ms = ss2 * ns, vars = sqs * ns - ms*ms;
        const float scr = g_rank[t] * rsqrtf(varr + 1e-5f);
        const float scs = g_suit[t] * rsqrtf(vars + 1e-5f);
        s_scale_r[t] = scr; s_shift_r[t] = be_rank[t] - mr * scr;
        s_scale_s[t] = scs; s_shift_s[t] = be_suit[t] - ms * scs;
    }
    __syncthreads();

    const float sc_r = s_scale_r[o], sh_r = s_shift_r[o];
    const float sc_s = s_scale_s[o], sh_s = s_shift_s[o];
#pragma unroll
    for (int u = 0; u < 4; ++u) {
        const int p = t + u*256;
        if (p < 960) {
            const int n = p >> 4;
            float v[16];
#pragma unroll
            for (int j = 0; j < 11; ++j) v[j]    = fmaxf(rv[u][j]*sc_r + sh_r, 0.f);
#pragma unroll
            for (int l = 0; l < 5; ++l)  v[11+l] = fmaxf(sv[u][l]*sc_s + sh_s, 0.f);
            float* rawp = raw + ((size_t)m*15360 + n*256 + o*16);
#pragma unroll
            for (int j = 0; j < 16; ++j) rawp[j] = v[j];
            float hh[32];
#pragma unroll
            for (int jj = 0; jj < 32; ++jj) {
                float a = s_bh1[jj];
#pragma unroll
                for (int i = 0; i < 16; ++i) a = fmaf(v[i], s_wh1[i*32 + jj], a);
                hh[jj] = fmaxf(a, 0.f);
            }
            char* rowp = apack + (size_t)(m*60 + n) * 2048 + o * 128;
#pragma unroll
            for (int c4 = 0; c4 < 4; ++c4) {
                ushort8 hi8, lo8;
#pragma unroll
                for (int j = 0; j < 8; ++j) {
                    const int jj = c4*8 + j;
                    float a = s_bh2[jj];
#pragma unroll
                    for (int i = 0; i < 32; ++i) a = fmaf(hh[i], s_wh2[i*32 + jj], a);
                    float xv = fmaxf(a, 0.f);
                    unsigned short hb = f2bf(xv);
                    float hf = bf2f(hb);
                    unsigned short lb = f2bf(xv - hf);
                    hi8[j] = hb; lo8[j] = lb;
                }
                *(ushort8*)(rowp + c4*32)      = hi8;
                *(ushort8*)(rowp + c4*32 + 16) = lo8;
            }
        }
    }
}

// ---------------------------------------------------------------------------
// K2: bf16x3 MFMA logits + per-(row, col-tile) top2.
// 256x256 tile, 8 waves (each 128x64: fr=8, fc=4), BK=32, double-buffered
// 2x64KB STATIC LDS, 2-phase pipeline: STAGE(next) -> COMPUTE(cur) ->
// vmcnt(0)+barrier. Grid 3600, XCD-swizzled (B-col slice L2-resident).
// ---------------------------------------------------------------------------
#define STAGE_K2(BB, K) do {                                                  \
    _Pragma("unroll")                                                         \
    for (int i_ = 0; i_ < 4; ++i_) {                                          \
        gl2lds16(aS[i_] + (K)*128, &s_lds[(BB) + dA[i_]]);                    \
        gl2lds16(bS[i_] + (K)*128, &s_lds[(BB) + 32768 + dA[i_]]);            \
    }                                                                         \
} while (0)

#define COMPUTE_K2(BB) do {                                                   \
    short8 ah[8], al[8];                                                      \
    _Pragma("unroll")                                                         \
    for (int fr = 0; fr < 8; ++fr) {                                          \
        const int row_ = wr*128 + fr*16 + (lane & 15);                        \
        const int ba_ = (BB) + row_*128 + (((lane >> 4) * 32) ^ ((row_ & 7) << 4)); \
        ah[fr] = *(const short8*)&s_lds[ba_];                                 \
        al[fr] = *(const short8*)&s_lds[ba_ ^ 16];                            \
    }                                                                         \
    __builtin_amdgcn_s_setprio(1);                                            \
    _Pragma("unroll")                                                         \
    for (int fc = 0; fc < 4; ++fc) {                                          \
        const int col_ = wc*64 + fc*16 + (lane & 15);                         \
        const int bb_ = (BB) + 32768 + col_*128 + (((lane >> 4) * 32) ^ ((col_ & 7) << 4)); \
        const short8 bh = *(const short8*)&s_lds[bb_];                        \
        const short8 bl = *(const short8*)&s_lds[bb_ ^ 16];                   \
        _Pragma("unroll")                                                     \
        for (int fr = 0; fr < 8; ++fr)                                        \
            acc[fr][fc] = __builtin_amdgcn_mfma_f32_16x16x32_bf16(ah[fr], bh, acc[fr][fc], 0, 0, 0); \
        _Pragma("unroll")                                                     \
        for (int fr = 0; fr < 8; ++fr)                                        \
            acc[fr][fc] = __builtin_amdgcn_mfma_f32_16x16x32_bf16(al[fr], bh, acc[fr][fc], 0, 0, 0); \
        _Pragma("unroll")                                                     \
        for (int fr = 0; fr < 8; ++fr)                                        \
            acc[fr][fc] = __builtin_amdgcn_mfma_f32_16x16x32_bf16(ah[fr], bl, acc[fr][fc], 0, 0, 0); \
    }                                                                         \
    __builtin_amdgcn_s_setprio(0);                                            \
} while (0)

__global__ __launch_bounds__(512, 2) void k2_mfma(
    const char* __restrict__ apack, const char* __restrict__ bpack,
    const float* __restrict__ b_cat, uint4* __restrict__ top2buf)
{
    __shared__ __align__(16) unsigned char s_lds[131072];   // 2 x (A 32KB | B 32KB)
    const int t = threadIdx.x;
    const int lane = t & 63;
    const int w  = t >> 6;
    const int wr = w >> 2, wc = w & 3;        // 2 row-halves x 4 col-quarters

    const int bid = blockIdx.x;
    const int swz = (bid & 7) * 450 + (bid >> 3);      // 3600 = 8 XCD x 450
    const int brow = swz % 120, bcol = swz / 120;      // brow fast: B-slice L2-resident
    const int row0 = brow * 256;
    const int col0 = bcol * 256;

    // staging: chunk c = i*512 + t; r = c>>3 (0..255), slot s = c&7 (16B),
    // global source pre-XOR-swizzled, LDS dest linear (wave-uniform base).
    const char* aS[4]; const char* bS[4]; int dA[4];
#pragma unroll
    for (int i = 0; i < 4; ++i) {
        const int c = i*512 + t, r = c >> 3, s = c & 7;
        aS[i] = apack + (size_t)(row0 + r) * 2048 + ((s ^ (r & 7)) << 4);
        bS[i] = bpack + (size_t)(col0 + r) * 2048 + ((s ^ (r & 7)) << 4);
        dA[i] = (i*512 + (t & 448)) * 16;
    }

    f32x4 acc[8][4] = {};

    // prologue
    STAGE_K2(0, 0);
    asm volatile("s_waitcnt vmcnt(0)" ::: "memory");
    __builtin_amdgcn_s_barrier();
    __builtin_amdgcn_sched_barrier(0);

    int cur = 0;
#pragma unroll 1
    for (int it = 0; it < 16; ++it) {
        if (it < 15) STAGE_K2(cur ^ 65536, it + 1);
        COMPUTE_K2(cur);
        asm volatile("s_waitcnt vmcnt(0)" ::: "memory");
        __builtin_amdgcn_s_barrier();
        __builtin_amdgcn_sched_barrier(0);
        cur ^= 65536;
    }

    // ---- epilogue: per-row top2 over this block's 256 cols ----
    uint4* sm = (uint4*)s_lds;   // [256 rows][4 wc] = 16KB (buf0, free now)
#pragma unroll
    for (int fr = 0; fr < 8; ++fr) {
#pragma unroll
        for (int reg = 0; reg < 4; ++reg) {
            float v1 = -3.0e38f, v2 = -3.0e38f;
            int   i1 = 0x7fffffff, i2 = 0x7fffffff;
#pragma unroll
            for (int fc = 0; fc < 4; ++fc) {
                const int colg = col0 + wc*64 + fc*16 + (lane & 15);
                const float v = (colg < NCLS) ? (acc[fr][fc][reg] + b_cat[colg]) : -3.0e38f;
                if (v > v1 || (v == v1 && colg < i1)) { v2=v1; i2=i1; v1=v; i1=colg; }
                else if (v > v2 || (v == v2 && colg < i2)) { v2=v; i2=colg; }
            }
#pragma unroll
            for (int off = 1; off < 16; off <<= 1) {
                const float w1 = __shfl_xor(v1, off, 64); const int j1 = __shfl_xor(i1, off, 64);
                const float w2 = __shfl_xor(v2, off, 64); const int j2 = __shfl_xor(i2, off, 64);
                if (w1 > v1 || (w1 == v1 && j1 < i1)) { v2=v1; i2=i1; v1=w1; i1=j1; }
                else if (w1 > v2 || (w1 == v2 && j1 < i2)) { v2=w1; i2=j1; }
                if (w2 > v1 || (w2 == v1 && j2 < i1)) { v2=v1; i2=i1; v1=w2; i1=j2; }
                else if (w2 > v2 || (w2 == v2 && j2 < i2)) { v2=w2; i2=j2; }
            }
            if ((lane & 15) == 0) {
                const int rl = wr*128 + fr*16 + (lane >> 4)*4 + reg;
                sm[rl*4 + wc] = make_uint4(__float_as_uint(v1), (unsigned)i1,
                                           __float_as_uint(v2), (unsigned)i2);
            }
        }
    }
    __syncthreads();
    if (t < 256) {
        float v1 = -3.0e38f, v2 = -3.0e38f;
        int   i1 = 0x7fffffff, i2 = 0x7fffffff;
#pragma unroll
        for (int q = 0; q < 4; ++q) {
            const uint4 e = sm[t*4 + q];
            const float a1 = __uint_as_float(e.x); const int b1 = (int)e.y;
            const float a2 = __uint_as_float(e.z); const int b2 = (int)e.w;
            if (a1 > v1 || (a1 == v1 && b1 < i1)) { v2=v1; i2=i1; v1=a1; i1=b1; }
            else if (a1 > v2 || (a1 == v2 && b1 < i2)) { v2=a1; i2=b1; }
            if (a2 > v1 || (a2 == v1 && b2 < i1)) { v2=v1; i2=i1; v1=a2; i1=b2; }
            else if (a2 > v2 || (a2 == v2 && b2 < i2)) { v2=a2; i2=b2; }
        }
        top2buf[(size_t)(row0 + t) * NTILE + bcol] =
            make_uint4(__float_as_uint(v1), (unsigned)i1, __float_as_uint(v2), (unsigned)i2);
    }
}

// ---------------------------------------------------------------------------
// K2b: reduce 30 tiles/row -> cls + near-tie fixup list
// ---------------------------------------------------------------------------
__global__ __launch_bounds__(256) void k2b_reduce(
    const uint4* __restrict__ top2buf, unsigned int* __restrict__ cls,
    unsigned int* __restrict__ list, unsigned int* __restrict__ cnt)
{
    const int row = blockIdx.x * 256 + threadIdx.x;
    float v1 = -3.0e38f, v2 = -3.0e38f;
    int   i1 = 0x7fffffff, i2 = 0x7fffffff;
    for (int tc = 0; tc < NTILE; ++tc) {
        const uint4 e = top2buf[(size_t)row * NTILE + tc];
        const float a1 = __uint_as_float(e.x); const int b1 = (int)e.y;
        const float a2 = __uint_as_float(e.z); const int b2 = (int)e.w;
        if (a1 > v1 || (a1 == v1 && b1 < i1)) { v2=v1; i2=i1; v1=a1; i1=b1; }
        else if (a1 > v2 || (a1 == v2 && b1 < i2)) { v2=a1; i2=b1; }
        if (a2 > v1 || (a2 == v1 && b2 < i1)) { v2=v1; i2=i1; v1=a2; i1=b2; }
        else if (a2 > v2 || (a2 == v2 && b2 < i2)) { v2=a2; i2=b2; }
    }
    cls[row] = (unsigned)i1;
    if (v1 - v2 <= TAU) {
        const unsigned s = atomicAdd(cnt, 1u);
        list[s] = (unsigned)row;
    }
}

// ---------------------------------------------------------------------------
// K2c: fp32 recompute of the 60 per-tile candidates for flagged rows.
// 1024 blocks, one flagged row per block iteration (fully parallel).
// ---------------------------------------------------------------------------
__global__ __launch_bounds__(256) void k2c_fixup(
    const char* __restrict__ apack, const char* __restrict__ bpack,
    const float* __restrict__ b_cat, const uint4* __restrict__ top2buf,
    const unsigned int* __restrict__ list, const unsigned int* __restrict__ cnt,
    unsigned int* __restrict__ cls)
{
    __shared__ float h[512];
    __shared__ float s_bv[4];
    __shared__ int   s_bi[4];
    const int t = threadIdx.x, lane = t & 63, wid = t >> 6;
    const int n = (int)*cnt;
    for (int idx = blockIdx.x; idx < n; idx += 1024) {
        const int row = (int)list[idx];
        __syncthreads();
        if (t < 64) {
            const ushort8 hi = *(const ushort8*)(apack + (size_t)row*2048 + t*32);
            const ushort8 lo = *(const ushort8*)(apack + (size_t)row*2048 + t*32 + 16);
#pragma unroll
            for (int j = 0; j < 8; ++j) h[t*8 + j] = bf2f(hi[j]) + bf2f(lo[j]);
        }
        __syncthreads();
        float bv = -3.0e38f; int bi = 0x7fffffff;
        for (int c = wid; c < 60; c += 4) {
            const uint4 e = top2buf[(size_t)row * NTILE + (c >> 1)];
            const int colc = (c & 1) ? (int)e.w : (int)e.y;
            const ushort8 bh = *(const ushort8*)(bpack + (size_t)colc*2048 + lane*32);
            const ushort8 bl = *(const ushort8*)(bpack + (size_t)colc*2048 + lane*32 + 16);
            float p = 0.f;
#pragma unroll
            for (int j = 0; j < 8; ++j) p += h[lane*8 + j] * (bf2f(bh[j]) + bf2f(bl[j]));
#pragma unroll
            for (int off = 1; off < 64; off <<= 1) p += __shfl_xor(p, off, 64);
            const float v = p + b_cat[colc];
            if (v > bv || (v == bv && colc < bi)) { bv = v; bi = colc; }
        }
        if (lane == 0) { s_bv[wid] = bv; s_bi[wid] = bi; }
        __syncthreads();
        if (t == 0) {
            float V = s_bv[0]; int I = s_bi[0];
#pragma unroll
            for (int wv = 1; wv < 4; ++wv)
                if (s_bv[wv] > V || (s_bv[wv] == V && s_bi[wv] < I)) { V = s_bv[wv]; I = s_bi[wv]; }
            cls[row] = (unsigned)I;
        }
    }
}

// ---------------------------------------------------------------------------
// K3: rr1 = raw(512,15360) @ w_o1(15360,512), split-K x8 fp32 atomicAdd
// ---------------------------------------------------------------------------
__global__ __launch_bounds__(256) void k3_rr1(
    const float* __restrict__ raw, const float* __restrict__ w_o1,
    float* __restrict__ rr1)
{
    __shared__ __align__(16) float Alds[16*64];
    __shared__ __align__(16) float Blds[16*64];
    const int t = threadIdx.x;
    const int row0 = blockIdx.x * 64;
    const int col0 = blockIdx.y * 64;
    const int ks   = blockIdx.z * 1920;

    float acc[4][4];
#pragma unroll
    for (int i = 0; i < 4; ++i)
#pragma unroll
        for (int j = 0; j < 4; ++j) acc[i][j] = 0.f;

    const int arow = t >> 2, akq = (t & 3) * 4;
    const int bk   = t >> 4, bc  = (t & 15) * 4;
    const float* Ag = raw  + (size_t)(row0 + arow) * RAWK + ks + akq;
    const float* Bg = w_o1 + (size_t)(ks + bk) * 512 + col0 + bc;

    for (int kc = 0; kc < 120; ++kc) {
        __syncthreads();
        const float4 a = *(const float4*)(Ag + kc*16);
        Alds[(akq+0)*64 + arow] = a.x;  Alds[(akq+1)*64 + arow] = a.y;
        Alds[(akq+2)*64 + arow] = a.z;  Alds[(akq+3)*64 + arow] = a.w;
        *(float4*)&Blds[bk*64 + bc] = *(const float4*)(Bg + (size_t)kc*16*512);
        __syncthreads();

        const int r0 = (t >> 4) * 4, c0 = (t & 15) * 4;
#pragma unroll
        for (int k = 0; k < 16; ++k) {
            float4 a4 = *(const float4*)&Alds[k*64 + r0];
            float4 b4 = *(const float4*)&Blds[k*64 + c0];
            acc[0][0]=fmaf(a4.x,b4.x,acc[0][0]); acc[0][1]=fmaf(a4.x,b4.y,acc[0][1]);
            acc[0][2]=fmaf(a4.x,b4.z,acc[0][2]); acc[0][3]=fmaf(a4.x,b4.w,acc[0][3]);
            acc[1][0]=fmaf(a4.y,b4.x,acc[1][0]); acc[1][1]=fmaf(a4.y,b4.y,acc[1][1]);
            acc[1][2]=fmaf(a4.y,b4.z,acc[1][2]); acc[1][3]=fmaf(a4.y,b4.w,acc[1][3]);
            acc[2][0]=fmaf(a4.z,b4.x,acc[2][0]); acc[2][1]=fmaf(a4.z,b4.y,acc[2][1]);
            acc[2][2]=fmaf(a4.z,b4.z,acc[2][2]); acc[2][3]=fmaf(a4.z,b4.w,acc[2][3]);
            acc[3][0]=fmaf(a4.w,b4.x,acc[3][0]); acc[3][1]=fmaf(a4.w,b4.y,acc[3][1]);
            acc[3][2]=fmaf(a4.w,b4.z,acc[3][2]); acc[3][3]=fmaf(a4.w,b4.w,acc[3][3]);
        }
    }
    const int r0 = (t >> 4) * 4, c0 = (t & 15) * 4;
#pragma unroll
    for (int i = 0; i < 4; ++i)
#pragma unroll
        for (int j = 0; j < 4; ++j)
            atomicAdd(&rr1[(size_t)(row0 + r0 + i)*512 + col0 + c0 + j], acc[i][j]);
}

// ---------------------------------------------------------------------------
// K4: per-m tail + best_hand(min of cls over 60) + final @ w_sc
// ---------------------------------------------------------------------------
__global__ __launch_bounds__(256) void k4_tail(
    const float* __restrict__ rr1, const float* __restrict__ b_o1,
    const unsigned int* __restrict__ cls,
    const float* __restrict__ w_o2, const float* __restrict__ b_o2,
    const float* __restrict__ w_o3, const float* __restrict__ b_o3,
    const float* __restrict__ w_sc, const float* __restrict__ b_sc,
    float* __restrict__ out)
{
    __shared__ float s1[512];
    __shared__ float s2[256];
    __shared__ float sf[128];
    __shared__ int s_best;
    const int t = threadIdx.x;
    const int m = blockIdx.x;

    if (t == 0) s_best = 0x7FFFFFFF;
    __syncthreads();
    for (int i = t; i < 512; i += 256)
        s1[i] = fmaxf(rr1[(size_t)m*512 + i] + b_o1[i], 0.f);
    if (t < 60) atomicMin(&s_best, (int)cls[m*60 + t]);
    __syncthreads();
    {
        float a = b_o2[t];
        for (int i = 0; i < 512; ++i) a = fmaf(s1[i], w_o2[i*256 + t], a);
        s2[t] = fmaxf(a, 0.f);
    }
    __syncthreads();
    if (t < 127) {
        float a = b_o3[t];
        for (int i = 0; i < 256; ++i) a = fmaf(s2[i], w_o3[i*127 + t], a);
        sf[t] = fmaxf(a, 0.f);
    }
    if (t == 0) sf[127] = (float)s_best;
    __syncthreads();
    if (t < 6) {
        float a = b_sc[t];
        for (int i = 0; i < 128; ++i) a = fmaf(sf[i], w_sc[i*6 + t], a);
        out[m*6 + t] = a;
    }
}

// ---------------------------------------------------------------------------
extern "C" void kernel_launch(void* const* d_in, const int* in_sizes, int n_in,
                              void* d_out, int out_size, void* d_ws, size_t ws_size,
                              hipStream_t stream)
{
    const int*   x       = (const int*)  d_in[0];
    const float* w_suit  = (const float*)d_in[1];
    const float* b_suit  = (const float*)d_in[2];
    const float* g_suit  = (const float*)d_in[3];
    const float* be_suit = (const float*)d_in[4];
    const float* w_rank  = (const float*)d_in[5];
    const float* b_rank  = (const float*)d_in[6];
    const float* g_rank  = (const float*)d_in[7];
    const float* be_rank = (const float*)d_in[8];
    const float* w_h1    = (const float*)d_in[9];
    const float* b_h1    = (const float*)d_in[10];
    const float* w_h2    = (const float*)d_in[11];
    const float* b_h2    = (const float*)d_in[12];
    const float* w_cat   = (const float*)d_in[13];
    const float* b_cat   = (const float*)d_in[14];
    const float* w_o1    = (const float*)d_in[15];
    const float* b_o1    = (const float*)d_in[16];
    const float* w_o2    = (const float*)d_in[17];
    const float* b_o2    = (const float*)d_in[18];
    const float* w_o3    = (const float*)d_in[19];
    const float* b_o3    = (const float*)d_in[20];
    const float* w_sc    = (const float*)d_in[21];
    const float* b_sc    = (const float*)d_in[22];
    float* out = (float*)d_out;

    char* ws = (char*)d_ws;
    float* raw   = (float*)(ws + OFF_RAW);
    char*  apack = ws + OFF_A;
    char*  bpack = ws + OFF_B;
    uint4* top2  = (uint4*)(ws + OFF_T2);
    float* rr1   = (float*)(ws + OFF_RR1);
    unsigned int* cls  = (unsigned int*)(ws + OFF_CLS);
    unsigned int* list = (unsigned int*)(ws + OFF_LIST);
    unsigned int* cnt  = (unsigned int*)(ws + OFF_CNT);

    hipMemsetAsync(rr1, 0, 512*512*sizeof(float), stream);
    hipMemsetAsync(cnt, 0, 256, stream);

    k0_pack<<<dim3(120, 8), 256, 0, stream>>>(w_cat, bpack);
    k1_features<<<512, 256, 0, stream>>>(x, w_suit, b_suit, g_suit, be_suit,
                                         w_rank, b_rank, g_rank, be_rank,
                                         w_h1, b_h1, w_h2, b_h2, raw, apack);
    k2_mfma<<<3600, 512, 0, stream>>>(apack, bpack, b_cat, top2);
    k2b_reduce<<<120, 256, 0, stream>>>(top2, cls, list, cnt);
    k2c_fixup<<<1024, 256, 0, stream>>>(apack, bpack, b_cat, top2, list, cnt, cls);
    k3_rr1<<<dim3(8, 8, 8), 256, 0, stream>>>(raw, w_o1, rr1);
    k4_tail<<<512, 256, 0, stream>>>(rr1, b_o1, cls, w_o2, b_o2, w_o3, b_o3,
                                     w_sc, b_sc, out);
}